// Round 2
// baseline (660.470 us; speedup 1.0000x reference)
//
#include <hip/hip_runtime.h>
#include <hip/hip_bf16.h>

#define BATCH 16
#define SEQ   2048
#define DIM   128
#define PITCH 72   // ushorts per LDS row: 64 data + 8 pad -> rows 16B-aligned, 2-way-max (free) b128 reads
#define SCALE 0.08838834764831845f  // 1/sqrt(128)

typedef __attribute__((ext_vector_type(8))) short short8;
typedef __attribute__((ext_vector_type(4))) float f32x4;

__device__ __forceinline__ unsigned short f2bf(float x) {
    unsigned int u = __float_as_uint(x);
    u += 0x7fffu + ((u >> 16) & 1u);   // round-to-nearest-even
    return (unsigned short)(u >> 16);
}
__device__ __forceinline__ float bf2f(unsigned short h) {
    return __uint_as_float(((unsigned int)h) << 16);
}
__device__ __forceinline__ void cvt_hl(float x, unsigned short& h, unsigned short& l) {
    h = f2bf(x);
    l = f2bf(x - bf2f(h));             // residual: together ~17 mantissa bits
}

// ---------------------------------------------------------------------------
// Kernel 1: E[b,q,k] = exp(scale * Q.K^T) written to attn region (unnormalized)
//           lsum[b,q] += row sums (atomic, zeroed by memset each launch)
// Grid (16 k-tiles, 16 q-tiles, 16 b), 256 thr. 128x128 tile, 4 waves 2x2,
// each wave 64x64 via 4x4 grid of 16x16x32 MFMAs, 3-term hi/lo split.
// ---------------------------------------------------------------------------
__global__ __launch_bounds__(256) void attn_scores_kernel(
    const float* __restrict__ Q, const float* __restrict__ Km,
    float* __restrict__ E, float* __restrict__ lsum)
{
    __shared__ unsigned short sQh[128 * PITCH];
    __shared__ unsigned short sQl[128 * PITCH];
    __shared__ unsigned short sKh[128 * PITCH];
    __shared__ unsigned short sKl[128 * PITCH];

    const int kt = blockIdx.x, qt = blockIdx.y, b = blockIdx.z;
    const int t = threadIdx.x;
    const int lane = t & 63, wave = t >> 6;
    const int quad = lane >> 4, l15 = lane & 15;
    const int wr = wave >> 1, wc = wave & 1;

    f32x4 acc[4][4];
#pragma unroll
    for (int i = 0; i < 4; ++i)
#pragma unroll
        for (int j = 0; j < 4; ++j)
            acc[i][j] = (f32x4){0.f, 0.f, 0.f, 0.f};

    const float* Qb = Q  + ((size_t)b * SEQ + (size_t)qt * 128) * DIM;
    const float* Kb = Km + ((size_t)b * SEQ + (size_t)kt * 128) * DIM;

#pragma unroll 1
    for (int dc = 0; dc < 2; ++dc) {      // stage D in two 64-wide chunks (LDS budget)
        __syncthreads();
#pragma unroll
        for (int it = 0; it < 8; ++it) {
            int i   = t + 256 * it;       // float4 index over 128 rows x 16 f4
            int row = i >> 4, c4 = i & 15;
            int gofs = row * DIM + dc * 64 + c4 * 4;
            int lofs = row * PITCH + c4 * 4;
            float4 q4 = *(const float4*)(Qb + gofs);
            ushort4 H, L;
            cvt_hl(q4.x, H.x, L.x); cvt_hl(q4.y, H.y, L.y);
            cvt_hl(q4.z, H.z, L.z); cvt_hl(q4.w, H.w, L.w);
            *(ushort4*)&sQh[lofs] = H;
            *(ushort4*)&sQl[lofs] = L;
            float4 k4 = *(const float4*)(Kb + gofs);
            cvt_hl(k4.x, H.x, L.x); cvt_hl(k4.y, H.y, L.y);
            cvt_hl(k4.z, H.z, L.z); cvt_hl(k4.w, H.w, L.w);
            *(ushort4*)&sKh[lofs] = H;
            *(ushort4*)&sKl[lofs] = L;
        }
        __syncthreads();
#pragma unroll
        for (int kk = 0; kk < 2; ++kk) {
            short8 ah[4], al[4], bh[4], bl[4];
#pragma unroll
            for (int i = 0; i < 4; ++i) {
                int off = (wr * 64 + i * 16 + l15) * PITCH + kk * 32 + quad * 8;
                ah[i] = *(const short8*)&sQh[off];
                al[i] = *(const short8*)&sQl[off];
            }
#pragma unroll
            for (int j = 0; j < 4; ++j) {
                int off = (wc * 64 + j * 16 + l15) * PITCH + kk * 32 + quad * 8;
                bh[j] = *(const short8*)&sKh[off];
                bl[j] = *(const short8*)&sKl[off];
            }
#pragma unroll
            for (int i = 0; i < 4; ++i)
#pragma unroll
                for (int j = 0; j < 4; ++j) {
                    acc[i][j] = __builtin_amdgcn_mfma_f32_16x16x32_bf16(ah[i], bh[j], acc[i][j], 0, 0, 0);
                    acc[i][j] = __builtin_amdgcn_mfma_f32_16x16x32_bf16(ah[i], bl[j], acc[i][j], 0, 0, 0);
                    acc[i][j] = __builtin_amdgcn_mfma_f32_16x16x32_bf16(al[i], bh[j], acc[i][j], 0, 0, 0);
                }
        }
    }

    // epilogue: E = exp(scale * s), row-sum -> atomic into lsum
    float* Eb = E + ((size_t)b * SEQ + (size_t)qt * 128 + wr * 64) * SEQ
                  + (size_t)kt * 128 + wc * 64;
    float* Lb = lsum + b * SEQ + qt * 128 + wr * 64;
#pragma unroll
    for (int i = 0; i < 4; ++i) {
        float rs0 = 0.f, rs1 = 0.f, rs2 = 0.f, rs3 = 0.f;
#pragma unroll
        for (int j = 0; j < 4; ++j) {
            f32x4 a = acc[i][j];
            float p0 = __expf(a[0] * SCALE);
            float p1 = __expf(a[1] * SCALE);
            float p2 = __expf(a[2] * SCALE);
            float p3 = __expf(a[3] * SCALE);
            size_t rb = (size_t)(i * 16 + quad * 4) * SEQ + j * 16 + l15;
            Eb[rb]           = p0;
            Eb[rb + SEQ]     = p1;
            Eb[rb + 2 * SEQ] = p2;
            Eb[rb + 3 * SEQ] = p3;
            rs0 += p0; rs1 += p1; rs2 += p2; rs3 += p3;
        }
        // reduce across the 16 lanes of each quad (cols); xor masks <16 stay in-group
        rs0 += __shfl_xor(rs0, 1); rs0 += __shfl_xor(rs0, 2);
        rs0 += __shfl_xor(rs0, 4); rs0 += __shfl_xor(rs0, 8);
        rs1 += __shfl_xor(rs1, 1); rs1 += __shfl_xor(rs1, 2);
        rs1 += __shfl_xor(rs1, 4); rs1 += __shfl_xor(rs1, 8);
        rs2 += __shfl_xor(rs2, 1); rs2 += __shfl_xor(rs2, 2);
        rs2 += __shfl_xor(rs2, 4); rs2 += __shfl_xor(rs2, 8);
        rs3 += __shfl_xor(rs3, 1); rs3 += __shfl_xor(rs3, 2);
        rs3 += __shfl_xor(rs3, 4); rs3 += __shfl_xor(rs3, 8);
        if (l15 == 0) {
            atomicAdd(&Lb[i * 16 + quad * 4 + 0], rs0);
            atomicAdd(&Lb[i * 16 + quad * 4 + 1], rs1);
            atomicAdd(&Lb[i * 16 + quad * 4 + 2], rs2);
            atomicAdd(&Lb[i * 16 + quad * 4 + 3], rs3);
        }
    }
}

// ---------------------------------------------------------------------------
// Kernel 2: normalize E in place (final attn weights) + out = P @ V (fused).
// Grid (32 q-tiles of 64, 16 b), 256 thr. Tile 64q x 128d, 4 waves 2x2
// (32q x 64d each, 2x4 MFMAs). V staged transposed (V^T[d][k]) for B-operand.
// ---------------------------------------------------------------------------
__global__ __launch_bounds__(256) void attn_out_kernel(
    const float* __restrict__ V, float* __restrict__ E,
    const float* __restrict__ lsum, float* __restrict__ O)
{
    __shared__ unsigned short sPh[64 * PITCH];
    __shared__ unsigned short sPl[64 * PITCH];
    __shared__ unsigned short sVh[128 * PITCH];
    __shared__ unsigned short sVl[128 * PITCH];
    __shared__ float sRl[64];

    const int qt = blockIdx.x, b = blockIdx.y;
    const int t = threadIdx.x;
    const int lane = t & 63, wave = t >> 6;
    const int quad = lane >> 4, l15 = lane & 15;
    const int wr = wave >> 1, wc = wave & 1;

    if (t < 64) sRl[t] = 1.0f / lsum[b * SEQ + qt * 64 + t];

    f32x4 acc[2][4];
#pragma unroll
    for (int i = 0; i < 2; ++i)
#pragma unroll
        for (int j = 0; j < 4; ++j)
            acc[i][j] = (f32x4){0.f, 0.f, 0.f, 0.f};

    float* Ebase = E + ((size_t)b * SEQ + (size_t)qt * 64) * SEQ;
    const float* Vbase = V + (size_t)b * SEQ * DIM;

#pragma unroll 1
    for (int kt = 0; kt < 32; ++kt) {
        __syncthreads();   // also covers sRl availability on kt==0
        // stage P: read E 64x64, scale by 1/l, write back (final weights), split to LDS
#pragma unroll
        for (int it = 0; it < 4; ++it) {
            int i = t + 256 * it;
            int row = i >> 4, c4 = i & 15;
            float* ep = Ebase + (size_t)row * SEQ + kt * 64 + c4 * 4;
            float4 e4 = *(const float4*)ep;
            float rl = sRl[row];
            e4.x *= rl; e4.y *= rl; e4.z *= rl; e4.w *= rl;
            *(float4*)ep = e4;
            ushort4 H, L;
            cvt_hl(e4.x, H.x, L.x); cvt_hl(e4.y, H.y, L.y);
            cvt_hl(e4.z, H.z, L.z); cvt_hl(e4.w, H.w, L.w);
            int lofs = row * PITCH + c4 * 4;
            *(ushort4*)&sPh[lofs] = H;
            *(ushort4*)&sPl[lofs] = L;
        }
        // stage V^T: V[kt*64+k][d] -> sV[d][k]  (coalesced global reads)
#pragma unroll
        for (int it = 0; it < 16; ++it) {
            int p = t + 256 * it;          // 0..4095 (d,k2) pairs
            int d = p & 127, k2 = p >> 7;  // k2 in 0..31 -> k = 2*k2, 2*k2+1
            const float* vp = Vbase + (size_t)(kt * 64 + 2 * k2) * DIM + d;
            float v0 = vp[0], v1 = vp[DIM];
            unsigned short h0, l0, h1, l1;
            cvt_hl(v0, h0, l0); cvt_hl(v1, h1, l1);
            *(ushort2*)&sVh[d * PITCH + 2 * k2] = make_ushort2(h0, h1);
            *(ushort2*)&sVl[d * PITCH + 2 * k2] = make_ushort2(l0, l1);
        }
        __syncthreads();
#pragma unroll
        for (int kk = 0; kk < 2; ++kk) {
            short8 ah[2], al[2], bh[4], bl[4];
#pragma unroll
            for (int i = 0; i < 2; ++i) {
                int off = (wr * 32 + i * 16 + l15) * PITCH + kk * 32 + quad * 8;
                ah[i] = *(const short8*)&sPh[off];
                al[i] = *(const short8*)&sPl[off];
            }
#pragma unroll
            for (int j = 0; j < 4; ++j) {
                int off = (wc * 64 + j * 16 + l15) * PITCH + kk * 32 + quad * 8;
                bh[j] = *(const short8*)&sVh[off];
                bl[j] = *(const short8*)&sVl[off];
            }
#pragma unroll
            for (int i = 0; i < 2; ++i)
#pragma unroll
                for (int j = 0; j < 4; ++j) {
                    acc[i][j] = __builtin_amdgcn_mfma_f32_16x16x32_bf16(ah[i], bh[j], acc[i][j], 0, 0, 0);
                    acc[i][j] = __builtin_amdgcn_mfma_f32_16x16x32_bf16(ah[i], bl[j], acc[i][j], 0, 0, 0);
                    acc[i][j] = __builtin_amdgcn_mfma_f32_16x16x32_bf16(al[i], bh[j], acc[i][j], 0, 0, 0);
                }
        }
    }

    float* Ob = O + ((size_t)b * SEQ + qt * 64 + wr * 32) * DIM + wc * 64;
#pragma unroll
    for (int i = 0; i < 2; ++i)
#pragma unroll
        for (int j = 0; j < 4; ++j)
#pragma unroll
            for (int r = 0; r < 4; ++r)
                Ob[(i * 16 + quad * 4 + r) * DIM + j * 16 + l15] = acc[i][j][r];
}

extern "C" void kernel_launch(void* const* d_in, const int* in_sizes, int n_in,
                              void* d_out, int out_size, void* d_ws, size_t ws_size,
                              hipStream_t stream) {
    const float* Q = (const float*)d_in[0];
    const float* K = (const float*)d_in[1];
    const float* V = (const float*)d_in[2];
    float* out  = (float*)d_out;
    float* attn = out + (size_t)BATCH * SEQ * DIM;   // outputs concatenated: (out, attn_weights)
    float* lsum = (float*)d_ws;                      // B*S floats = 128 KB

    hipMemsetAsync(lsum, 0, (size_t)BATCH * SEQ * sizeof(float), stream);
    attn_scores_kernel<<<dim3(16, 16, 16), 256, 0, stream>>>(Q, K, attn, lsum);
    attn_out_kernel<<<dim3(32, 16), 256, 0, stream>>>(V, attn, lsum, out);
}